// Round 12
// baseline (547.636 us; speedup 1.0000x reference)
//
#include <hip/hip_runtime.h>
#include <math.h>

#define DIM 256
#define NROWS_TILE 128
#define SPLITS 8
#define NCAND SPLITS                // one wave owns each row: 1 slot per split
#define CODES_PER_SPLIT 1024        // K / SPLITS, K = 8192
#define WCH 16                      // codes per wave-chunk (x half-K)
#define NCT (CODES_PER_SPLIT / WCH) // 64 code-tiles (x2 k-halves = 128 chunks)

typedef __attribute__((ext_vector_type(8))) _Float16 f16x8;
typedef __attribute__((ext_vector_type(4))) _Float16 f16x4;
typedef __attribute__((ext_vector_type(4))) float f32x4;

__device__ __forceinline__ void gload16(const void* g, void* l) {
    __builtin_amdgcn_global_load_lds(
        (const __attribute__((address_space(1))) void*)g,
        (__attribute__((address_space(3))) void*)l, 16, 0, 0);
}

__device__ __forceinline__ float waveReduceSum(float v) {
#pragma unroll
    for (int off = 32; off >= 1; off >>= 1) v += __shfl_xor(v, off, 64);
    return v;
}

// ---------- prep: row-l2norm + split-f16 encode (hi + lo*2048) ----------
__global__ __launch_bounds__(256) void k_prep(const float* __restrict__ in,
        _Float16* __restrict__ hi, _Float16* __restrict__ lo,
        float* __restrict__ norms, int nrows)
{
    const int w = threadIdx.x >> 6, lane = threadIdx.x & 63;
    const int r = blockIdx.x * 4 + w;
    if (r >= nrows) return;
    f32x4 v = *(const f32x4*)&in[(size_t)r * DIM + lane * 4];
    float ss = waveReduceSum(v[0]*v[0] + v[1]*v[1] + v[2]*v[2] + v[3]*v[3]);
    const float n = fmaxf(sqrtf(ss), 1e-12f);
    if (norms != nullptr && lane == 0) norms[r] = n;
    f32x4 f;
    f[0] = v[0] / n; f[1] = v[1] / n; f[2] = v[2] / n; f[3] = v[3] / n;
    f16x4 h, l;
#pragma unroll
    for (int c = 0; c < 4; ++c) {
        h[c] = (_Float16)f[c];
        l[c] = (_Float16)((f[c] - (float)h[c]) * 2048.0f);
    }
    *(f16x4*)&hi[(size_t)r * DIM + lane * 4] = h;
    *(f16x4*)&lo[(size_t)r * DIM + lane * 4] = l;
}

// ---------- main: split-f16 MFMA GEMM-BT, A in regs, wave-private LDS ----------
// grid: (N/128 row tiles, SPLITS=8). Block 256 thr = 4 waves; wave owns 32 rows
// x full K=256 in regs. Each wave stages its OWN 16-code x 128-k x {hi,lo}
// chunk (8 KB) into a private ring-2 LDS buffer and computes only that chunk:
// ZERO barriers; sync = intra-wave counted vmcnt(8). LDS read traffic /4 vs
// shared-panel design (each frag read by exactly one wave). 8 resident waves
// free-run -> ds_read bursts and MFMA bursts of different waves overlap.
__global__ __launch_bounds__(256, 2) void k_gemm(
    const _Float16* __restrict__ fnh, const _Float16* __restrict__ fnl,
    const _Float16* __restrict__ enh, const _Float16* __restrict__ enl,
    float* __restrict__ cand_val, int* __restrict__ cand_idx)
{
    // per wave: 2 ring bufs x 4096 f16 (8 KB). buf layout: [Bh: kc(4) x 512 |
    // Bl: +2048]; slot lane*8 = en?[(cb+(lane&15))*256 + kh*128 + kc*32 + (lane>>4)*8]
    __shared__ _Float16 smem[4 * 8192];   // 64 KB, wave w owns [w*8192, +8192)

    const int t = threadIdx.x;
    const int w = t >> 6, lane = t & 63;
    const int rbase = blockIdx.x * NROWS_TILE;
    const int cbase = blockIdx.y * CODES_PER_SPLIT;
    const int koff = (lane >> 4) * 8;

    // ---- A panel into registers: wave w rows rbase+w*32 .. +31, full K ----
    f16x8 Ah[2][8], Al[2][8];
    {
        const size_t arow = (size_t)(rbase + w * 32 + (lane & 15)) * DIM;
#pragma unroll
        for (int i = 0; i < 2; ++i)
#pragma unroll
            for (int kc = 0; kc < 8; ++kc) {
                Ah[i][kc] = *(const f16x8*)&fnh[arow + (size_t)i * 16 * DIM + kc * 32 + koff];
                Al[i][kc] = *(const f16x8*)&fnl[arow + (size_t)i * 16 * DIM + kc * 32 + koff];
            }
    }
    asm volatile("s_waitcnt vmcnt(0)" ::: "memory");   // A drained; vmcnt clean

    _Float16* const mybuf0 = &smem[w * 8192];
    _Float16* const mybuf1 = mybuf0 + 4096;

    // per-lane incremental global pointers (code-tile 0 of this split)
    const _Float16* gh = enh + (size_t)(cbase + (lane & 15)) * DIM + koff;
    const _Float16* gl = enl + (size_t)(cbase + (lane & 15)) * DIM + koff;

    float bestv[2][4];
    int   bestc[2][4];
#pragma unroll
    for (int i = 0; i < 2; ++i)
#pragma unroll
        for (int rg = 0; rg < 4; ++rg) { bestv[i][rg] = -2.0f; bestc[i][rg] = 0; }

    const f32x4 ZERO4 = (f32x4){0.f, 0.f, 0.f, 0.f};

#define STAGE(KH, DST) do {                                                   \
        _Pragma("unroll")                                                     \
        for (int f = 0; f < 4; ++f) {                                         \
            gload16(gh + (KH) * 128 + f * 32, (DST) + f * 512);               \
            gload16(gl + (KH) * 128 + f * 32, (DST) + 2048 + f * 512);        \
        }                                                                     \
    } while (0)

    // prologue: chunk (ct=0, kh=0) in flight
    STAGE(0, mybuf0);

    f32x4 acc0[2], acc1[2];

#pragma unroll 1
    for (int ct = 0; ct < NCT; ++ct) {
        // ---- kh = 0: stage (ct,1), wait (ct,0), compute ----
        STAGE(1, mybuf1);
        asm volatile("s_waitcnt vmcnt(8)" ::: "memory");   // (ct,0) landed
#pragma unroll
        for (int kc = 0; kc < 4; ++kc) {
            const f16x8 Bh = *(const f16x8*)(mybuf0 + kc * 512 + lane * 8);
            const f16x8 Bl = *(const f16x8*)(mybuf0 + 2048 + kc * 512 + lane * 8);
            if (kc == 0) {
#pragma unroll
                for (int i = 0; i < 2; ++i) {
                    acc0[i] = __builtin_amdgcn_mfma_f32_16x16x32_f16(Ah[i][0], Bh, ZERO4, 0, 0, 0);
                    acc1[i] = __builtin_amdgcn_mfma_f32_16x16x32_f16(Al[i][0], Bh, ZERO4, 0, 0, 0);
                    acc1[i] = __builtin_amdgcn_mfma_f32_16x16x32_f16(Ah[i][0], Bl, acc1[i], 0, 0, 0);
                }
            } else {
#pragma unroll
                for (int i = 0; i < 2; ++i) {
                    acc0[i] = __builtin_amdgcn_mfma_f32_16x16x32_f16(Ah[i][kc], Bh, acc0[i], 0, 0, 0);
                    acc1[i] = __builtin_amdgcn_mfma_f32_16x16x32_f16(Al[i][kc], Bh, acc1[i], 0, 0, 0);
                    acc1[i] = __builtin_amdgcn_mfma_f32_16x16x32_f16(Ah[i][kc], Bl, acc1[i], 0, 0, 0);
                }
            }
        }

        // ---- kh = 1: stage (ct+1,0), wait (ct,1), compute + argmax ----
        if (ct + 1 < NCT) {
            gh += WCH * DIM; gl += WCH * DIM;
            STAGE(0, mybuf0);
            asm volatile("s_waitcnt vmcnt(8)" ::: "memory");   // (ct,1) landed
        } else {
            asm volatile("s_waitcnt vmcnt(0)" ::: "memory");
        }
#pragma unroll
        for (int kc = 0; kc < 4; ++kc) {
            const f16x8 Bh = *(const f16x8*)(mybuf1 + kc * 512 + lane * 8);
            const f16x8 Bl = *(const f16x8*)(mybuf1 + 2048 + kc * 512 + lane * 8);
#pragma unroll
            for (int i = 0; i < 2; ++i) {
                acc0[i] = __builtin_amdgcn_mfma_f32_16x16x32_f16(Ah[i][4 + kc], Bh, acc0[i], 0, 0, 0);
                acc1[i] = __builtin_amdgcn_mfma_f32_16x16x32_f16(Al[i][4 + kc], Bh, acc1[i], 0, 0, 0);
                acc1[i] = __builtin_amdgcn_mfma_f32_16x16x32_f16(Ah[i][4 + kc], Bl, acc1[i], 0, 0, 0);
            }
        }

        // lane-local argmax (code = cb + (lane&15)); codes strictly increase
        // per lane across ct, so strict > keeps first occurrence.
        const int cb = cbase + ct * WCH;
#pragma unroll
        for (int i = 0; i < 2; ++i)
#pragma unroll
            for (int rg = 0; rg < 4; ++rg) {
                const float vv = acc0[i][rg] + acc1[i][rg] * (1.0f / 2048.0f);
                if (vv > bestv[i][rg]) { bestv[i][rg] = vv; bestc[i][rg] = cb; }
            }
    }
#undef STAGE

    // final cross-lane argmax (width 16), min-index tie-break
#pragma unroll
    for (int i = 0; i < 2; ++i)
#pragma unroll
        for (int rg = 0; rg < 4; ++rg) {
            float bv = bestv[i][rg];
            int bix = bestc[i][rg] + (lane & 15);
#pragma unroll
            for (int off = 1; off < 16; off <<= 1) {
                const float ov = __shfl_xor(bv, off, 16);
                const int oi = __shfl_xor(bix, off, 16);
                if (ov > bv || (ov == bv && oi < bix)) { bv = ov; bix = oi; }
            }
            if ((lane & 15) == 0) {
                const int r = rbase + w * 32 + i * 16 + (lane >> 4) * 4 + rg;
                cand_val[(size_t)r * NCAND + blockIdx.y] = bv;
                cand_idx[(size_t)r * NCAND + blockIdx.y] = bix;
            }
        }
}

// ---------- merge splits + gather quantize + scatter embed_sum ----------
__global__ __launch_bounds__(256) void k_merge(
    const float* __restrict__ x, const float* __restrict__ embed,
    const float* __restrict__ cand_val, const int* __restrict__ cand_idx,
    const float* __restrict__ xnorm,
    float* __restrict__ quantize, float* __restrict__ ind_out,
    float* __restrict__ embed_sum, float* __restrict__ bins)
{
    const int w = threadIdx.x >> 6, lane = threadIdx.x & 63;
    const int r = blockIdx.x * 4 + w;
    float v = -3e30f; int ix = 0x7fffffff;
    if (lane < NCAND) {
        v = cand_val[(size_t)r * NCAND + lane];
        ix = cand_idx[(size_t)r * NCAND + lane];
    }
#pragma unroll
    for (int off = 1; off < 8; off <<= 1) {
        const float ov = __shfl_xor(v, off, 8);
        const int oi = __shfl_xor(ix, off, 8);
        if (ov > v || (ov == v && oi < ix)) { v = ov; ix = oi; }
    }
    ix = __shfl(ix, 0, 64);
    if (lane == 0) {
        ind_out[r] = (float)ix;
        atomicAdd(&bins[ix], 1.0f);
    }
    f32x4 e = *(const f32x4*)&embed[(size_t)ix * DIM + lane * 4];
    *(f32x4*)&quantize[(size_t)r * DIM + lane * 4] = e;
    f32x4 xv = *(const f32x4*)&x[(size_t)r * DIM + lane * 4];
    const float n = xnorm[r];
    atomicAdd(&embed_sum[(size_t)ix * DIM + lane * 4 + 0], xv[0] / n);
    atomicAdd(&embed_sum[(size_t)ix * DIM + lane * 4 + 1], xv[1] / n);
    atomicAdd(&embed_sum[(size_t)ix * DIM + lane * 4 + 2], xv[2] / n);
    atomicAdd(&embed_sum[(size_t)ix * DIM + lane * 4 + 3], xv[3] / n);
}

// ---------- EMA update (en recomputed inline) ----------
__global__ __launch_bounds__(256) void k_update(const float* __restrict__ embed,
    const float* __restrict__ embed_sum, const float* __restrict__ bins,
    float* __restrict__ embed_new, int K)
{
    const int w = threadIdx.x >> 6, lane = threadIdx.x & 63;
    const int k = blockIdx.x * 4 + w;
    if (k >= K) return;
    f32x4 e = *(const f32x4*)&embed[(size_t)k * DIM + lane * 4];
    float sse = waveReduceSum(e[0]*e[0] + e[1]*e[1] + e[2]*e[2] + e[3]*e[3]);
    const float ne = fmaxf(sqrtf(sse), 1e-12f);

    const float b = bins[k];
    const float bs = (b == 0.f) ? 1.f : b;
    f32x4 s = *(const f32x4*)&embed_sum[(size_t)k * DIM + lane * 4];
    f32x4 vv;
    vv[0] = s[0] / bs; vv[1] = s[1] / bs; vv[2] = s[2] / bs; vv[3] = s[3] / bs;
    float ssv = waveReduceSum(vv[0]*vv[0] + vv[1]*vv[1] + vv[2]*vv[2] + vv[3]*vv[3]);
    const float nv = fmaxf(sqrtf(ssv), 1e-12f);

    f32x4 o;
#pragma unroll
    for (int c = 0; c < 4; ++c) {
        const float norm_c = (b == 0.f) ? (e[c] / ne) : (vv[c] / nv);
        o[c] = 0.8f * e[c] + 0.2f * norm_c;
    }
    *(f32x4*)&embed_new[(size_t)k * DIM + lane * 4] = o;
}

extern "C" void kernel_launch(void* const* d_in, const int* in_sizes, int n_in,
                              void* d_out, int out_size, void* d_ws, size_t ws_size,
                              hipStream_t stream) {
    const float* x = (const float*)d_in[0];
    const float* embed = (const float*)d_in[1];
    const int N = in_sizes[0] / DIM;   // 16384
    const int K = in_sizes[1] / DIM;   // 8192

    float* quantize  = (float*)d_out;
    float* ind_out   = quantize + (size_t)N * DIM;
    float* embed_new = ind_out + N;

    char* ws = (char*)d_ws;
    _Float16* fnh = (_Float16*)ws;                               // [0, 8M)
    _Float16* fnl = (_Float16*)(ws + (size_t)N * DIM * 2);       // [8M, 16M)
    _Float16* enh = (_Float16*)(ws + (size_t)N * DIM * 4);       // [16M, 20M)
    _Float16* enl = (_Float16*)(ws + (size_t)N * DIM * 4 + (size_t)K * DIM * 2);
    char* p = ws + (size_t)N * DIM * 4 + (size_t)K * DIM * 4;    // 24M
    float* xnorm    = (float*)p;                 p += (size_t)N * 4;
    float* cand_val = (float*)p;                 p += (size_t)N * NCAND * 4;
    int*   cand_idx = (int*)p;
    // embed_sum/bins alias fnh/fnl (dead after k_gemm)
    float* embed_sum = (float*)ws;               // K*DIM floats = 8 MB
    float* bins      = embed_sum + (size_t)K * DIM;

    k_prep<<<(N + 3) / 4, 256, 0, stream>>>(x, fnh, fnl, xnorm, N);
    k_prep<<<(K + 3) / 4, 256, 0, stream>>>(embed, enh, enl, nullptr, K);

    dim3 grid(N / NROWS_TILE, SPLITS);
    k_gemm<<<grid, 256, 0, stream>>>(fnh, fnl, enh, enl, cand_val, cand_idx);

    hipMemsetAsync(embed_sum, 0, ((size_t)K * DIM + K) * sizeof(float), stream);

    k_merge<<<(N + 3) / 4, 256, 0, stream>>>(x, embed, cand_val, cand_idx, xnorm,
                                             quantize, ind_out, embed_sum, bins);
    k_update<<<(K + 3) / 4, 256, 0, stream>>>(embed, embed_sum, bins, embed_new, K);
}

// Round 13
// 261.578 us; speedup vs baseline: 2.0936x; 2.0936x over previous
//
#include <hip/hip_runtime.h>
#include <math.h>

#define DIM 256
#define NROWS_TILE 128
#define SPLITS 8
#define NCAND SPLITS                // one wave owns each row: 1 slot per split
#define CODES_PER_SPLIT 1024        // K / SPLITS, K = 8192
#define CCH 32                      // codes per phase (full K=256 staged)
#define NPH (CODES_PER_SPLIT / CCH) // 32 phases
#define BUF_F16 16384               // 32 KB: [Bh: 16 steps x 512 | Bl: +8192]

typedef __attribute__((ext_vector_type(8))) _Float16 f16x8;
typedef __attribute__((ext_vector_type(4))) _Float16 f16x4;
typedef __attribute__((ext_vector_type(4))) float f32x4;

__device__ __forceinline__ void gload16(const void* g, void* l) {
    __builtin_amdgcn_global_load_lds(
        (const __attribute__((address_space(1))) void*)g,
        (__attribute__((address_space(3))) void*)l, 16, 0, 0);
}

__device__ __forceinline__ float waveReduceSum(float v) {
#pragma unroll
    for (int off = 32; off >= 1; off >>= 1) v += __shfl_xor(v, off, 64);
    return v;
}

// ---------- prep: row-l2norm + split-f16 encode (hi + lo*2048) ----------
__global__ __launch_bounds__(256) void k_prep(const float* __restrict__ in,
        _Float16* __restrict__ hi, _Float16* __restrict__ lo,
        float* __restrict__ norms, int nrows)
{
    const int w = threadIdx.x >> 6, lane = threadIdx.x & 63;
    const int r = blockIdx.x * 4 + w;
    if (r >= nrows) return;
    f32x4 v = *(const f32x4*)&in[(size_t)r * DIM + lane * 4];
    float ss = waveReduceSum(v[0]*v[0] + v[1]*v[1] + v[2]*v[2] + v[3]*v[3]);
    const float n = fmaxf(sqrtf(ss), 1e-12f);
    if (norms != nullptr && lane == 0) norms[r] = n;
    f32x4 f;
    f[0] = v[0] / n; f[1] = v[1] / n; f[2] = v[2] / n; f[3] = v[3] / n;
    f16x4 h, l;
#pragma unroll
    for (int c = 0; c < 4; ++c) {
        h[c] = (_Float16)f[c];
        l[c] = (_Float16)((f[c] - (float)h[c]) * 2048.0f);
    }
    *(f16x4*)&hi[(size_t)r * DIM + lane * 4] = h;
    *(f16x4*)&lo[(size_t)r * DIM + lane * 4] = l;
}

// ---------- main: split-f16 MFMA GEMM-BT, A in registers ----------
// grid: (N/128 row tiles, SPLITS=8). Block 256 thr = 4 waves; wave owns 32
// rows x full K=256 in regs. Phase = 32 codes x K=256 x {hi,lo} = 32 KB chunk,
// ring-2 (64 KB LDS), publish protocol: vmcnt(0) -> barrier -> stage(c+1) ->
// compute(c). Inner loop: explicit 3-slot B register queue, reads issued 2
// steps ahead of their MFMA consumers -> wave never stalls on lgkmcnt ->
// its MFMA demand is continuous -> LDS port (82us) overlaps MFMA pipe (95us)
// instead of serializing (R10 measured them back-to-back: 7013 cyc/round).
__global__ __launch_bounds__(256, 2) void k_gemm(
    const _Float16* __restrict__ fnh, const _Float16* __restrict__ fnl,
    const _Float16* __restrict__ enh, const _Float16* __restrict__ enl,
    float* __restrict__ cand_val, int* __restrict__ cand_idx)
{
    // buf (f16 units): Bh step s at s*512, Bl at 8192 + s*512; slot lane*8 =
    // en?[(cb+(s>>3)*16+(lane&15))*256 + (s&7)*32 + (lane>>4)*8]
    __shared__ _Float16 smem[2][BUF_F16];   // 2 x 32 KB

    const int t = threadIdx.x;
    const int w = t >> 6, lane = t & 63;
    const int rbase = blockIdx.x * NROWS_TILE;
    const int cbase = blockIdx.y * CODES_PER_SPLIT;
    const int koff = (lane >> 4) * 8;

    // ---- A panel into registers: wave w rows rbase+w*32 .. +31, full K ----
    f16x8 Ah[2][8], Al[2][8];
    {
        const size_t arow = (size_t)(rbase + w * 32 + (lane & 15)) * DIM;
#pragma unroll
        for (int i = 0; i < 2; ++i)
#pragma unroll
            for (int kc = 0; kc < 8; ++kc) {
                Ah[i][kc] = *(const f16x8*)&fnh[arow + (size_t)i * 16 * DIM + kc * 32 + koff];
                Al[i][kc] = *(const f16x8*)&fnl[arow + (size_t)i * 16 * DIM + kc * 32 + koff];
            }
    }
    asm volatile("s_waitcnt vmcnt(0)" ::: "memory");   // A done; vmcnt clean

    // staging roles: wave w stages mat = w>>1 (0=hi,1=lo), col-half ch = w&1
    const _Float16* const bsrc = (w < 2) ? enh : enl;
    const int dstoff = (w >> 1) * 8192 + (w & 1) * 4096;

    // per-lane incremental global pointer (chunk 0), bumped +CCH*DIM per stage
    const _Float16* gptr = bsrc + (size_t)(cbase + (w & 1) * 16 + (lane & 15)) * DIM + koff;

    float bestv[2][4];
    int   bestc[2][4];
#pragma unroll
    for (int i = 0; i < 2; ++i)
#pragma unroll
        for (int rg = 0; rg < 4; ++rg) { bestv[i][rg] = -2.0f; bestc[i][rg] = 0; }

    const f32x4 ZERO4 = (f32x4){0.f, 0.f, 0.f, 0.f};

    // prologue: chunk 0 in flight
    {
        _Float16* l0 = &smem[0][dstoff];
#pragma unroll
        for (int q = 0; q < 8; ++q)
            gload16(gptr + q * 32, l0 + q * 512);
        gptr += CCH * DIM;
    }

#pragma unroll 1
    for (int c = 0; c < NPH; ++c) {
        const int buf = c & 1;
        // publish chunk c: own loads drained BEFORE the barrier (per-wave vmcnt
        // is the only cross-wave visibility mechanism for global_load_lds).
        asm volatile("s_waitcnt vmcnt(0)" ::: "memory");
        __builtin_amdgcn_s_barrier();
        // stage chunk c+1 into the retired buffer; full compute phase to land.
        if (c + 1 < NPH) {
            _Float16* l0 = &smem[buf ^ 1][dstoff];
#pragma unroll
            for (int q = 0; q < 8; ++q)
                gload16(gptr + q * 32, l0 + q * 512);
            gptr += CCH * DIM;
        }

        const _Float16* bufp = &smem[buf][0];
        f32x4 acc0[2][2], acc1a[2][2], acc1b[2][2];   // [ch][i]

        // ---- 16 steps, B reads issued 2 steps ahead (3-slot static queue) ----
        f16x8 QH[3], QL[3];
        QH[0] = *(const f16x8*)(bufp + 0 * 512 + lane * 8);
        QL[0] = *(const f16x8*)(bufp + 8192 + 0 * 512 + lane * 8);
        QH[1] = *(const f16x8*)(bufp + 1 * 512 + lane * 8);
        QL[1] = *(const f16x8*)(bufp + 8192 + 1 * 512 + lane * 8);
#pragma unroll
        for (int s = 0; s < 16; ++s) {
            if (s + 2 < 16) {
                QH[(s + 2) % 3] = *(const f16x8*)(bufp + (s + 2) * 512 + lane * 8);
                QL[(s + 2) % 3] = *(const f16x8*)(bufp + 8192 + (s + 2) * 512 + lane * 8);
            }
            const int ch = s >> 3;          // compile-time under full unroll
            const int kc = s & 7;
            const f16x8 Bh = QH[s % 3];
            const f16x8 Bl = QL[s % 3];
            if (kc == 0) {
#pragma unroll
                for (int i = 0; i < 2; ++i) {
                    acc0[ch][i]  = __builtin_amdgcn_mfma_f32_16x16x32_f16(Ah[i][0], Bh, ZERO4, 0, 0, 0);
                    acc1a[ch][i] = __builtin_amdgcn_mfma_f32_16x16x32_f16(Ah[i][0], Bl, ZERO4, 0, 0, 0);
                    acc1b[ch][i] = __builtin_amdgcn_mfma_f32_16x16x32_f16(Al[i][0], Bh, ZERO4, 0, 0, 0);
                }
            } else {
#pragma unroll
                for (int i = 0; i < 2; ++i) {
                    acc0[ch][i]  = __builtin_amdgcn_mfma_f32_16x16x32_f16(Ah[i][kc], Bh, acc0[ch][i],  0, 0, 0);
                    acc1a[ch][i] = __builtin_amdgcn_mfma_f32_16x16x32_f16(Ah[i][kc], Bl, acc1a[ch][i], 0, 0, 0);
                    acc1b[ch][i] = __builtin_amdgcn_mfma_f32_16x16x32_f16(Al[i][kc], Bh, acc1b[ch][i], 0, 0, 0);
                }
            }
        }

        // lane-local argmax: codes strictly increase per lane, so strict >
        // alone preserves first-occurrence semantics.
        const int cb = cbase + c * CCH;
#pragma unroll
        for (int ch = 0; ch < 2; ++ch)
#pragma unroll
            for (int i = 0; i < 2; ++i)
#pragma unroll
                for (int rg = 0; rg < 4; ++rg) {
                    const float vv = acc0[ch][i][rg] +
                        (acc1a[ch][i][rg] + acc1b[ch][i][rg]) * (1.0f / 2048.0f);
                    if (vv > bestv[i][rg]) { bestv[i][rg] = vv; bestc[i][rg] = cb + ch * 16; }
                }
    }

    // final cross-lane argmax (width 16), min-index tie-break
#pragma unroll
    for (int i = 0; i < 2; ++i)
#pragma unroll
        for (int rg = 0; rg < 4; ++rg) {
            float bv = bestv[i][rg];
            int bix = bestc[i][rg] + (lane & 15);
#pragma unroll
            for (int off = 1; off < 16; off <<= 1) {
                const float ov = __shfl_xor(bv, off, 16);
                const int oi = __shfl_xor(bix, off, 16);
                if (ov > bv || (ov == bv && oi < bix)) { bv = ov; bix = oi; }
            }
            if ((lane & 15) == 0) {
                const int r = rbase + w * 32 + i * 16 + (lane >> 4) * 4 + rg;
                cand_val[(size_t)r * NCAND + blockIdx.y] = bv;
                cand_idx[(size_t)r * NCAND + blockIdx.y] = bix;
            }
        }
}

// ---------- merge splits + gather quantize + scatter embed_sum ----------
__global__ __launch_bounds__(256) void k_merge(
    const float* __restrict__ x, const float* __restrict__ embed,
    const float* __restrict__ cand_val, const int* __restrict__ cand_idx,
    const float* __restrict__ xnorm,
    float* __restrict__ quantize, float* __restrict__ ind_out,
    float* __restrict__ embed_sum, float* __restrict__ bins)
{
    const int w = threadIdx.x >> 6, lane = threadIdx.x & 63;
    const int r = blockIdx.x * 4 + w;
    float v = -3e30f; int ix = 0x7fffffff;
    if (lane < NCAND) {
        v = cand_val[(size_t)r * NCAND + lane];
        ix = cand_idx[(size_t)r * NCAND + lane];
    }
#pragma unroll
    for (int off = 1; off < 8; off <<= 1) {
        const float ov = __shfl_xor(v, off, 8);
        const int oi = __shfl_xor(ix, off, 8);
        if (ov > v || (ov == v && oi < ix)) { v = ov; ix = oi; }
    }
    ix = __shfl(ix, 0, 64);
    if (lane == 0) {
        ind_out[r] = (float)ix;
        atomicAdd(&bins[ix], 1.0f);
    }
    f32x4 e = *(const f32x4*)&embed[(size_t)ix * DIM + lane * 4];
    *(f32x4*)&quantize[(size_t)r * DIM + lane * 4] = e;
    f32x4 xv = *(const f32x4*)&x[(size_t)r * DIM + lane * 4];
    const float n = xnorm[r];
    atomicAdd(&embed_sum[(size_t)ix * DIM + lane * 4 + 0], xv[0] / n);
    atomicAdd(&embed_sum[(size_t)ix * DIM + lane * 4 + 1], xv[1] / n);
    atomicAdd(&embed_sum[(size_t)ix * DIM + lane * 4 + 2], xv[2] / n);
    atomicAdd(&embed_sum[(size_t)ix * DIM + lane * 4 + 3], xv[3] / n);
}

// ---------- EMA update (en recomputed inline) ----------
__global__ __launch_bounds__(256) void k_update(const float* __restrict__ embed,
    const float* __restrict__ embed_sum, const float* __restrict__ bins,
    float* __restrict__ embed_new, int K)
{
    const int w = threadIdx.x >> 6, lane = threadIdx.x & 63;
    const int k = blockIdx.x * 4 + w;
    if (k >= K) return;
    f32x4 e = *(const f32x4*)&embed[(size_t)k * DIM + lane * 4];
    float sse = waveReduceSum(e[0]*e[0] + e[1]*e[1] + e[2]*e[2] + e[3]*e[3]);
    const float ne = fmaxf(sqrtf(sse), 1e-12f);

    const float b = bins[k];
    const float bs = (b == 0.f) ? 1.f : b;
    f32x4 s = *(const f32x4*)&embed_sum[(size_t)k * DIM + lane * 4];
    f32x4 vv;
    vv[0] = s[0] / bs; vv[1] = s[1] / bs; vv[2] = s[2] / bs; vv[3] = s[3] / bs;
    float ssv = waveReduceSum(vv[0]*vv[0] + vv[1]*vv[1] + vv[2]*vv[2] + vv[3]*vv[3]);
    const float nv = fmaxf(sqrtf(ssv), 1e-12f);

    f32x4 o;
#pragma unroll
    for (int c = 0; c < 4; ++c) {
        const float norm_c = (b == 0.f) ? (e[c] / ne) : (vv[c] / nv);
        o[c] = 0.8f * e[c] + 0.2f * norm_c;
    }
    *(f32x4*)&embed_new[(size_t)k * DIM + lane * 4] = o;
}

extern "C" void kernel_launch(void* const* d_in, const int* in_sizes, int n_in,
                              void* d_out, int out_size, void* d_ws, size_t ws_size,
                              hipStream_t stream) {
    const float* x = (const float*)d_in[0];
    const float* embed = (const float*)d_in[1];
    const int N = in_sizes[0] / DIM;   // 16384
    const int K = in_sizes[1] / DIM;   // 8192

    float* quantize  = (float*)d_out;
    float* ind_out   = quantize + (size_t)N * DIM;
    float* embed_new = ind_out + N;

    char* ws = (char*)d_ws;
    _Float16* fnh = (_Float16*)ws;                               // [0, 8M)
    _Float16* fnl = (_Float16*)(ws + (size_t)N * DIM * 2);       // [8M, 16M)
    _Float16* enh = (_Float16*)(ws + (size_t)N * DIM * 4);       // [16M, 20M)
    _Float16* enl = (_Float16*)(ws + (size_t)N * DIM * 4 + (size_t)K * DIM * 2);
    char* p = ws + (size_t)N * DIM * 4 + (size_t)K * DIM * 4;    // 24M
    float* xnorm    = (float*)p;                 p += (size_t)N * 4;
    float* cand_val = (float*)p;                 p += (size_t)N * NCAND * 4;
    int*   cand_idx = (int*)p;
    // embed_sum/bins alias fnh/fnl (dead after k_gemm)
    float* embed_sum = (float*)ws;               // K*DIM floats = 8 MB
    float* bins      = embed_sum + (size_t)K * DIM;

    k_prep<<<(N + 3) / 4, 256, 0, stream>>>(x, fnh, fnl, xnorm, N);
    k_prep<<<(K + 3) / 4, 256, 0, stream>>>(embed, enh, enl, nullptr, K);

    dim3 grid(N / NROWS_TILE, SPLITS);
    k_gemm<<<grid, 256, 0, stream>>>(fnh, fnl, enh, enl, cand_val, cand_idx);

    hipMemsetAsync(embed_sum, 0, ((size_t)K * DIM + K) * sizeof(float), stream);

    k_merge<<<(N + 3) / 4, 256, 0, stream>>>(x, embed, cand_val, cand_idx, xnorm,
                                             quantize, ind_out, embed_sum, bins);
    k_update<<<(K + 3) / 4, 256, 0, stream>>>(embed, embed_sum, bins, embed_new, K);
}

// Round 14
// 260.572 us; speedup vs baseline: 2.1017x; 1.0039x over previous
//
#include <hip/hip_runtime.h>
#include <math.h>

#define DIM 256
#define NROWS_TILE 128
#define SPLITS 8
#define NCAND SPLITS                // one wave owns each row: 1 slot per split
#define CODES_PER_SPLIT 1024        // K / SPLITS, K = 8192
#define CCH 32                      // codes per phase (full K=256 staged)
#define NPH (CODES_PER_SPLIT / CCH) // 32 phases
#define BUF_F16 16384               // 32 KB: [Bh: 16 steps x 512 | Bl: +8192]

typedef __attribute__((ext_vector_type(8))) _Float16 f16x8;
typedef __attribute__((ext_vector_type(4))) _Float16 f16x4;
typedef __attribute__((ext_vector_type(4))) float f32x4;

__device__ __forceinline__ void gload16(const void* g, void* l) {
    __builtin_amdgcn_global_load_lds(
        (const __attribute__((address_space(1))) void*)g,
        (__attribute__((address_space(3))) void*)l, 16, 0, 0);
}

__device__ __forceinline__ float waveReduceSum(float v) {
#pragma unroll
    for (int off = 32; off >= 1; off >>= 1) v += __shfl_xor(v, off, 64);
    return v;
}

// ---------- prep: row-l2norm + split-f16 encode (hi + lo*2048) ----------
__global__ __launch_bounds__(256) void k_prep(const float* __restrict__ in,
        _Float16* __restrict__ hi, _Float16* __restrict__ lo,
        float* __restrict__ norms, int nrows)
{
    const int w = threadIdx.x >> 6, lane = threadIdx.x & 63;
    const int r = blockIdx.x * 4 + w;
    if (r >= nrows) return;
    f32x4 v = *(const f32x4*)&in[(size_t)r * DIM + lane * 4];
    float ss = waveReduceSum(v[0]*v[0] + v[1]*v[1] + v[2]*v[2] + v[3]*v[3]);
    const float n = fmaxf(sqrtf(ss), 1e-12f);
    if (norms != nullptr && lane == 0) norms[r] = n;
    f32x4 f;
    f[0] = v[0] / n; f[1] = v[1] / n; f[2] = v[2] / n; f[3] = v[3] / n;
    f16x4 h, l;
#pragma unroll
    for (int c = 0; c < 4; ++c) {
        h[c] = (_Float16)f[c];
        l[c] = (_Float16)((f[c] - (float)h[c]) * 2048.0f);
    }
    *(f16x4*)&hi[(size_t)r * DIM + lane * 4] = h;
    *(f16x4*)&lo[(size_t)r * DIM + lane * 4] = l;
}

// ---------- main: split-f16 MFMA GEMM-BT, A in registers ----------
// grid: (N/128 row tiles, SPLITS=8). Block 256 thr = 4 waves; wave owns 32
// rows x full K=256 in regs. Phase = 32 codes x K=256 x {hi,lo} = 32 KB chunk,
// ring-2 (64 KB LDS), publish protocol: vmcnt(0) -> barrier -> stage(c+1) ->
// compute(c).
// ANTI-PHASE STAGGER: the 2 co-resident blocks/CU (pairs (b, b+256) for this
// 1024-block grid filled 2-deep) start phase-SYNCED and convoy: both read-
// burst together (MFMA pipe idle) then MFMA-burst together (LDS port idle) --
// R10/R13 counters close exactly at port 3072 + pipe 3725 = 6797 ~= 7013
// cyc/phase measured. A one-time ~3.6k-cyc s_sleep for odd dispatch layers
// ((bid>>8)&1) anti-phases the pair; contention makes anti-phase the stable
// attractor (drifting toward sync slows your own reads -> pushed back).
__global__ __launch_bounds__(256, 2) void k_gemm(
    const _Float16* __restrict__ fnh, const _Float16* __restrict__ fnl,
    const _Float16* __restrict__ enh, const _Float16* __restrict__ enl,
    float* __restrict__ cand_val, int* __restrict__ cand_idx)
{
    // buf (f16 units): Bh step s at s*512, Bl at 8192 + s*512; slot lane*8 =
    // en?[(cb+(s>>3)*16+(lane&15))*256 + (s&7)*32 + (lane>>4)*8]
    __shared__ _Float16 smem[2][BUF_F16];   // 2 x 32 KB

    const int t = threadIdx.x;
    const int w = t >> 6, lane = t & 63;
    const int rbase = blockIdx.x * NROWS_TILE;
    const int cbase = blockIdx.y * CODES_PER_SPLIT;
    const int koff = (lane >> 4) * 8;

    // ---- anti-phase stagger: odd dispatch layer sleeps ~half a phase ----
    const int bid = blockIdx.x + gridDim.x * blockIdx.y;
    if ((bid >> 8) & 1) {
#pragma unroll
        for (int sl = 0; sl < 7; ++sl) __builtin_amdgcn_s_sleep(8);   // ~3.6k cyc
    }

    // ---- A panel into registers: wave w rows rbase+w*32 .. +31, full K ----
    f16x8 Ah[2][8], Al[2][8];
    {
        const size_t arow = (size_t)(rbase + w * 32 + (lane & 15)) * DIM;
#pragma unroll
        for (int i = 0; i < 2; ++i)
#pragma unroll
            for (int kc = 0; kc < 8; ++kc) {
                Ah[i][kc] = *(const f16x8*)&fnh[arow + (size_t)i * 16 * DIM + kc * 32 + koff];
                Al[i][kc] = *(const f16x8*)&fnl[arow + (size_t)i * 16 * DIM + kc * 32 + koff];
            }
    }
    asm volatile("s_waitcnt vmcnt(0)" ::: "memory");   // A done; vmcnt clean

    // staging roles: wave w stages mat = w>>1 (0=hi,1=lo), col-half ch = w&1
    const _Float16* const bsrc = (w < 2) ? enh : enl;
    const int dstoff = (w >> 1) * 8192 + (w & 1) * 4096;

    // per-lane incremental global pointer (chunk 0), bumped +CCH*DIM per stage
    const _Float16* gptr = bsrc + (size_t)(cbase + (w & 1) * 16 + (lane & 15)) * DIM + koff;

    float bestv[2][4];
    int   bestc[2][4];
#pragma unroll
    for (int i = 0; i < 2; ++i)
#pragma unroll
        for (int rg = 0; rg < 4; ++rg) { bestv[i][rg] = -2.0f; bestc[i][rg] = 0; }

    const f32x4 ZERO4 = (f32x4){0.f, 0.f, 0.f, 0.f};

    // prologue: chunk 0 in flight
    {
        _Float16* l0 = &smem[0][dstoff];
#pragma unroll
        for (int q = 0; q < 8; ++q)
            gload16(gptr + q * 32, l0 + q * 512);
        gptr += CCH * DIM;
    }

#pragma unroll 1
    for (int c = 0; c < NPH; ++c) {
        const int buf = c & 1;
        // publish chunk c: own loads drained BEFORE the barrier (per-wave vmcnt
        // is the only cross-wave visibility mechanism for global_load_lds).
        asm volatile("s_waitcnt vmcnt(0)" ::: "memory");
        __builtin_amdgcn_s_barrier();
        // stage chunk c+1 into the retired buffer; full compute phase to land.
        if (c + 1 < NPH) {
            _Float16* l0 = &smem[buf ^ 1][dstoff];
#pragma unroll
            for (int q = 0; q < 8; ++q)
                gload16(gptr + q * 32, l0 + q * 512);
            gptr += CCH * DIM;
        }

        const _Float16* bufp = &smem[buf][0];
        f32x4 acc0[2][2], acc1a[2][2], acc1b[2][2];   // [ch][i]

        // ---- 16 steps, B reads issued 2 steps ahead (3-slot static queue) ----
        f16x8 QH[3], QL[3];
        QH[0] = *(const f16x8*)(bufp + 0 * 512 + lane * 8);
        QL[0] = *(const f16x8*)(bufp + 8192 + 0 * 512 + lane * 8);
        QH[1] = *(const f16x8*)(bufp + 1 * 512 + lane * 8);
        QL[1] = *(const f16x8*)(bufp + 8192 + 1 * 512 + lane * 8);
#pragma unroll
        for (int s = 0; s < 16; ++s) {
            if (s + 2 < 16) {
                QH[(s + 2) % 3] = *(const f16x8*)(bufp + (s + 2) * 512 + lane * 8);
                QL[(s + 2) % 3] = *(const f16x8*)(bufp + 8192 + (s + 2) * 512 + lane * 8);
            }
            const int ch = s >> 3;          // compile-time under full unroll
            const int kc = s & 7;
            const f16x8 Bh = QH[s % 3];
            const f16x8 Bl = QL[s % 3];
            if (kc == 0) {
#pragma unroll
                for (int i = 0; i < 2; ++i) {
                    acc0[ch][i]  = __builtin_amdgcn_mfma_f32_16x16x32_f16(Ah[i][0], Bh, ZERO4, 0, 0, 0);
                    acc1a[ch][i] = __builtin_amdgcn_mfma_f32_16x16x32_f16(Ah[i][0], Bl, ZERO4, 0, 0, 0);
                    acc1b[ch][i] = __builtin_amdgcn_mfma_f32_16x16x32_f16(Al[i][0], Bh, ZERO4, 0, 0, 0);
                }
            } else {
#pragma unroll
                for (int i = 0; i < 2; ++i) {
                    acc0[ch][i]  = __builtin_amdgcn_mfma_f32_16x16x32_f16(Ah[i][kc], Bh, acc0[ch][i],  0, 0, 0);
                    acc1a[ch][i] = __builtin_amdgcn_mfma_f32_16x16x32_f16(Ah[i][kc], Bl, acc1a[ch][i], 0, 0, 0);
                    acc1b[ch][i] = __builtin_amdgcn_mfma_f32_16x16x32_f16(Al[i][kc], Bh, acc1b[ch][i], 0, 0, 0);
                }
            }
        }

        // lane-local argmax: codes strictly increase per lane, so strict >
        // alone preserves first-occurrence semantics.
        const int cb = cbase + c * CCH;
#pragma unroll
        for (int ch = 0; ch < 2; ++ch)
#pragma unroll
            for (int i = 0; i < 2; ++i)
#pragma unroll
                for (int rg = 0; rg < 4; ++rg) {
                    const float vv = acc0[ch][i][rg] +
                        (acc1a[ch][i][rg] + acc1b[ch][i][rg]) * (1.0f / 2048.0f);
                    if (vv > bestv[i][rg]) { bestv[i][rg] = vv; bestc[i][rg] = cb + ch * 16; }
                }
    }

    // final cross-lane argmax (width 16), min-index tie-break
#pragma unroll
    for (int i = 0; i < 2; ++i)
#pragma unroll
        for (int rg = 0; rg < 4; ++rg) {
            float bv = bestv[i][rg];
            int bix = bestc[i][rg] + (lane & 15);
#pragma unroll
            for (int off = 1; off < 16; off <<= 1) {
                const float ov = __shfl_xor(bv, off, 16);
                const int oi = __shfl_xor(bix, off, 16);
                if (ov > bv || (ov == bv && oi < bix)) { bv = ov; bix = oi; }
            }
            if ((lane & 15) == 0) {
                const int r = rbase + w * 32 + i * 16 + (lane >> 4) * 4 + rg;
                cand_val[(size_t)r * NCAND + blockIdx.y] = bv;
                cand_idx[(size_t)r * NCAND + blockIdx.y] = bix;
            }
        }
}

// ---------- merge splits + gather quantize + scatter embed_sum ----------
__global__ __launch_bounds__(256) void k_merge(
    const float* __restrict__ x, const float* __restrict__ embed,
    const float* __restrict__ cand_val, const int* __restrict__ cand_idx,
    const float* __restrict__ xnorm,
    float* __restrict__ quantize, float* __restrict__ ind_out,
    float* __restrict__ embed_sum, float* __restrict__ bins)
{
    const int w = threadIdx.x >> 6, lane = threadIdx.x & 63;
    const int r = blockIdx.x * 4 + w;
    float v = -3e30f; int ix = 0x7fffffff;
    if (lane < NCAND) {
        v = cand_val[(size_t)r * NCAND + lane];
        ix = cand_idx[(size_t)r * NCAND + lane];
    }
#pragma unroll
    for (int off = 1; off < 8; off <<= 1) {
        const float ov = __shfl_xor(v, off, 8);
        const int oi = __shfl_xor(ix, off, 8);
        if (ov > v || (ov == v && oi < ix)) { v = ov; ix = oi; }
    }
    ix = __shfl(ix, 0, 64);
    if (lane == 0) {
        ind_out[r] = (float)ix;
        atomicAdd(&bins[ix], 1.0f);
    }
    f32x4 e = *(const f32x4*)&embed[(size_t)ix * DIM + lane * 4];
    *(f32x4*)&quantize[(size_t)r * DIM + lane * 4] = e;
    f32x4 xv = *(const f32x4*)&x[(size_t)r * DIM + lane * 4];
    const float n = xnorm[r];
    atomicAdd(&embed_sum[(size_t)ix * DIM + lane * 4 + 0], xv[0] / n);
    atomicAdd(&embed_sum[(size_t)ix * DIM + lane * 4 + 1], xv[1] / n);
    atomicAdd(&embed_sum[(size_t)ix * DIM + lane * 4 + 2], xv[2] / n);
    atomicAdd(&embed_sum[(size_t)ix * DIM + lane * 4 + 3], xv[3] / n);
}

// ---------- EMA update (en recomputed inline) ----------
__global__ __launch_bounds__(256) void k_update(const float* __restrict__ embed,
    const float* __restrict__ embed_sum, const float* __restrict__ bins,
    float* __restrict__ embed_new, int K)
{
    const int w = threadIdx.x >> 6, lane = threadIdx.x & 63;
    const int k = blockIdx.x * 4 + w;
    if (k >= K) return;
    f32x4 e = *(const f32x4*)&embed[(size_t)k * DIM + lane * 4];
    float sse = waveReduceSum(e[0]*e[0] + e[1]*e[1] + e[2]*e[2] + e[3]*e[3]);
    const float ne = fmaxf(sqrtf(sse), 1e-12f);

    const float b = bins[k];
    const float bs = (b == 0.f) ? 1.f : b;
    f32x4 s = *(const f32x4*)&embed_sum[(size_t)k * DIM + lane * 4];
    f32x4 vv;
    vv[0] = s[0] / bs; vv[1] = s[1] / bs; vv[2] = s[2] / bs; vv[3] = s[3] / bs;
    float ssv = waveReduceSum(vv[0]*vv[0] + vv[1]*vv[1] + vv[2]*vv[2] + vv[3]*vv[3]);
    const float nv = fmaxf(sqrtf(ssv), 1e-12f);

    f32x4 o;
#pragma unroll
    for (int c = 0; c < 4; ++c) {
        const float norm_c = (b == 0.f) ? (e[c] / ne) : (vv[c] / nv);
        o[c] = 0.8f * e[c] + 0.2f * norm_c;
    }
    *(f32x4*)&embed_new[(size_t)k * DIM + lane * 4] = o;
}

extern "C" void kernel_launch(void* const* d_in, const int* in_sizes, int n_in,
                              void* d_out, int out_size, void* d_ws, size_t ws_size,
                              hipStream_t stream) {
    const float* x = (const float*)d_in[0];
    const float* embed = (const float*)d_in[1];
    const int N = in_sizes[0] / DIM;   // 16384
    const int K = in_sizes[1] / DIM;   // 8192

    float* quantize  = (float*)d_out;
    float* ind_out   = quantize + (size_t)N * DIM;
    float* embed_new = ind_out + N;

    char* ws = (char*)d_ws;
    _Float16* fnh = (_Float16*)ws;                               // [0, 8M)
    _Float16* fnl = (_Float16*)(ws + (size_t)N * DIM * 2);       // [8M, 16M)
    _Float16* enh = (_Float16*)(ws + (size_t)N * DIM * 4);       // [16M, 20M)
    _Float16* enl = (_Float16*)(ws + (size_t)N * DIM * 4 + (size_t)K * DIM * 2);
    char* p = ws + (size_t)N * DIM * 4 + (size_t)K * DIM * 4;    // 24M
    float* xnorm    = (float*)p;                 p += (size_t)N * 4;
    float* cand_val = (float*)p;                 p += (size_t)N * NCAND * 4;
    int*   cand_idx = (int*)p;
    // embed_sum/bins alias fnh/fnl (dead after k_gemm)
    float* embed_sum = (float*)ws;               // K*DIM floats = 8 MB
    float* bins      = embed_sum + (size_t)K * DIM;

    k_prep<<<(N + 3) / 4, 256, 0, stream>>>(x, fnh, fnl, xnorm, N);
    k_prep<<<(K + 3) / 4, 256, 0, stream>>>(embed, enh, enl, nullptr, K);

    dim3 grid(N / NROWS_TILE, SPLITS);
    k_gemm<<<grid, 256, 0, stream>>>(fnh, fnl, enh, enl, cand_val, cand_idx);

    hipMemsetAsync(embed_sum, 0, ((size_t)K * DIM + K) * sizeof(float), stream);

    k_merge<<<(N + 3) / 4, 256, 0, stream>>>(x, embed, cand_val, cand_idx, xnorm,
                                             quantize, ind_out, embed_sum, bins);
    k_update<<<(K + 3) / 4, 256, 0, stream>>>(embed, embed_sum, bins, embed_new, K);
}

// Round 15
// 185.348 us; speedup vs baseline: 2.9546x; 1.4059x over previous
//
#include <hip/hip_runtime.h>
#include <math.h>

#define DIM 256
#define NROWS_TILE 128
#define SPLITS 8
#define CODES_PER_SPLIT 1024        // K / SPLITS
#define CCH 32                      // codes per phase (full K=256 staged)
#define NPH (CODES_PER_SPLIT / CCH) // 32 phases
#define BUF_F16 8192                // 16 KB: 16 frags x 512 f16 (Bh only)
#define DELTA 2.2e-3f               // > 2x rigorous |exact - hi.hi| bound (9.8e-4)

typedef __attribute__((ext_vector_type(8))) _Float16 f16x8;
typedef __attribute__((ext_vector_type(4))) _Float16 f16x4;
typedef __attribute__((ext_vector_type(4))) float f32x4;

__device__ __forceinline__ void gload16(const void* g, void* l) {
    __builtin_amdgcn_global_load_lds(
        (const __attribute__((address_space(1))) void*)g,
        (__attribute__((address_space(3))) void*)l, 16, 0, 0);
}

__device__ __forceinline__ float waveReduceSum(float v) {
#pragma unroll
    for (int off = 32; off >= 1; off >>= 1) v += __shfl_xor(v, off, 64);
    return v;
}

// ---------- prep: row-l2norm + f16 hi encode + norm output ----------
__global__ __launch_bounds__(256) void k_prep(const float* __restrict__ in,
        _Float16* __restrict__ hi, float* __restrict__ norms, int nrows)
{
    const int w = threadIdx.x >> 6, lane = threadIdx.x & 63;
    const int r = blockIdx.x * 4 + w;
    if (r >= nrows) return;
    f32x4 v = *(const f32x4*)&in[(size_t)r * DIM + lane * 4];
    float ss = waveReduceSum(v[0]*v[0] + v[1]*v[1] + v[2]*v[2] + v[3]*v[3]);
    const float n = fmaxf(sqrtf(ss), 1e-12f);
    if (lane == 0) norms[r] = n;
    f16x4 h;
#pragma unroll
    for (int c = 0; c < 4; ++c) h[c] = (_Float16)(v[c] / n);
    *(f16x4*)&hi[(size_t)r * DIM + lane * 4] = h;
}

// ---------- main: hi-only f16 MFMA GEMM-BT + top-2/slot, top-4/(row,split) ----------
// grid: (N/128, SPLITS). 4 waves; wave owns 32 rows x K=256 in regs (64 VGPR).
// Phase = 32 codes x 256 k (Bh only) = 16 KB, ring-2, publish protocol as R13.
// Certified-refine scheme: pass 1 tracks top-2 per lane-slot; epilogue extracts
// top-4 per (row,split); k_merge refines rows whose top gap < DELTA with exact
// fp32 dots. |exact - hi.hi| <= 9.8e-4 (C-S bound), DELTA = 2.2e-3.
__global__ __launch_bounds__(256, 2) void k_gemm(
    const _Float16* __restrict__ fnh, const _Float16* __restrict__ enh,
    float* __restrict__ cand_val, int* __restrict__ cand_idx)
{
    // buf: frag s (ch=s>>3, kc=s&7) at s*512; slot lane*8 =
    // enh[(cb+ch*16+(lane&15))*256 + kc*32 + (lane>>4)*8]
    __shared__ _Float16 smem[2][BUF_F16];   // 2 x 16 KB

    const int t = threadIdx.x;
    const int w = t >> 6, lane = t & 63;
    const int rbase = blockIdx.x * NROWS_TILE;
    const int cbase = blockIdx.y * CODES_PER_SPLIT;
    const int koff = (lane >> 4) * 8;

    // ---- A panel (hi only): wave w rows rbase+w*32 .. +31, full K ----
    f16x8 Ah[2][8];
    {
        const size_t arow = (size_t)(rbase + w * 32 + (lane & 15)) * DIM;
#pragma unroll
        for (int i = 0; i < 2; ++i)
#pragma unroll
            for (int kc = 0; kc < 8; ++kc)
                Ah[i][kc] = *(const f16x8*)&fnh[arow + (size_t)i * 16 * DIM + kc * 32 + koff];
    }
    asm volatile("s_waitcnt vmcnt(0)" ::: "memory");   // A done; vmcnt clean

    // staging roles: wave w stages frags w*4..w*4+3 (ch = w>>1, kc base = (w&1)*4)
    const int chbase = (w >> 1) * 16;
    const int kcb = (w & 1) * 4;
    const int dstoff = w * 2048;
    const _Float16* gptr = enh + (size_t)(cbase + chbase + (lane & 15)) * DIM + kcb * 32 + koff;

    // per-lane-slot top-2 tracking (slot = (i,rg); code = stored + (lane&15))
    float v1[2][4], v2[2][4];
    int   c1[2][4], c2[2][4];
#pragma unroll
    for (int i = 0; i < 2; ++i)
#pragma unroll
        for (int rg = 0; rg < 4; ++rg) {
            v1[i][rg] = -2.0f; v2[i][rg] = -2.5f;
            c1[i][rg] = 0;     c2[i][rg] = 0;
        }

    const f32x4 ZERO4 = (f32x4){0.f, 0.f, 0.f, 0.f};

    // prologue: chunk 0 in flight
    {
        _Float16* l0 = &smem[0][dstoff];
#pragma unroll
        for (int q = 0; q < 4; ++q)
            gload16(gptr + q * 32, l0 + q * 512);
        gptr += CCH * DIM;
    }

#pragma unroll 1
    for (int c = 0; c < NPH; ++c) {
        const int buf = c & 1;
        asm volatile("s_waitcnt vmcnt(0)" ::: "memory");   // publish own loads
        __builtin_amdgcn_s_barrier();
        if (c + 1 < NPH) {
            _Float16* l0 = &smem[buf ^ 1][dstoff];
#pragma unroll
            for (int q = 0; q < 4; ++q)
                gload16(gptr + q * 32, l0 + q * 512);
            gptr += CCH * DIM;
        }

        const _Float16* bufp = &smem[buf][0];
        f32x4 acc[2][2];   // [ch][i]

#pragma unroll
        for (int s = 0; s < 16; ++s) {
            const int ch = s >> 3;
            const int kc = s & 7;
            const f16x8 Bh = *(const f16x8*)(bufp + s * 512 + lane * 8);
            if (kc == 0) {
#pragma unroll
                for (int i = 0; i < 2; ++i)
                    acc[ch][i] = __builtin_amdgcn_mfma_f32_16x16x32_f16(Ah[i][0], Bh, ZERO4, 0, 0, 0);
            } else {
#pragma unroll
                for (int i = 0; i < 2; ++i)
                    acc[ch][i] = __builtin_amdgcn_mfma_f32_16x16x32_f16(Ah[i][kc], Bh, acc[ch][i], 0, 0, 0);
            }
        }

        // top-2 update per slot; codes ascend per lane -> strict > keeps first
        const int cb = cbase + c * CCH;
#pragma unroll
        for (int ch = 0; ch < 2; ++ch)
#pragma unroll
            for (int i = 0; i < 2; ++i)
#pragma unroll
                for (int rg = 0; rg < 4; ++rg) {
                    const float vv = acc[ch][i][rg];
                    const int cd = cb + ch * 16;
                    const bool gt1 = vv > v1[i][rg];
                    const bool gt2 = vv > v2[i][rg];
                    const float nv2 = gt1 ? v1[i][rg] : (gt2 ? vv : v2[i][rg]);
                    const int   nc2 = gt1 ? c1[i][rg] : (gt2 ? cd : c2[i][rg]);
                    v2[i][rg] = nv2; c2[i][rg] = nc2;
                    v1[i][rg] = gt1 ? vv : v1[i][rg];
                    c1[i][rg] = gt1 ? cd : c1[i][rg];
                }
    }

    // epilogue: per slot, extract top-4 of the 16-lane code group
#pragma unroll
    for (int i = 0; i < 2; ++i)
#pragma unroll
        for (int rg = 0; rg < 4; ++rg) {
            float lv1 = v1[i][rg], lv2 = v2[i][rg];
            int   li1 = c1[i][rg] + (lane & 15);
            int   li2 = c2[i][rg] + (lane & 15);
            const int r = rbase + w * 32 + i * 16 + (lane >> 4) * 4 + rg;
            const size_t base = ((size_t)r * SPLITS + blockIdx.y) * 4;
#pragma unroll
            for (int p = 0; p < 4; ++p) {
                float mv = lv1; int mi = li1;
#pragma unroll
                for (int off = 1; off < 16; off <<= 1) {
                    const float ov = __shfl_xor(mv, off, 16);
                    const int oi = __shfl_xor(mi, off, 16);
                    if (ov > mv || (ov == mv && oi < mi)) { mv = ov; mi = oi; }
                }
                if ((lane & 15) == 0) {
                    cand_val[base + p] = mv;
                    cand_idx[base + p] = mi;
                }
                if (li1 == mi) {   // demote owner (indices unique)
                    lv1 = lv2; li1 = li2;
                    lv2 = -3e30f; li2 = 0x7fffffff;
                }
            }
        }
}

// ---------- merge: top-4 global, certified refine, gather + scatter ----------
__global__ __launch_bounds__(256) void k_merge(
    const float* __restrict__ x, const float* __restrict__ embed,
    const float* __restrict__ cand_val, const int* __restrict__ cand_idx,
    const float* __restrict__ xnorm, const float* __restrict__ enorm,
    float* __restrict__ quantize, float* __restrict__ ind_out,
    float* __restrict__ embed_sum, float* __restrict__ bins)
{
    const int w = threadIdx.x >> 6, lane = threadIdx.x & 63;
    const int r = blockIdx.x * 4 + w;
    const int NC = SPLITS * 4;   // 32 candidates

    float lv = -3e30f; int li = 0x7fffffff;
    if (lane < NC) {
        lv = cand_val[(size_t)r * NC + lane];
        li = cand_idx[(size_t)r * NC + lane];
    }
    float tv[4]; int ti[4];
#pragma unroll
    for (int p = 0; p < 4; ++p) {
        float mv = lv; int mi = li;
#pragma unroll
        for (int off = 1; off < 32; off <<= 1) {
            const float ov = __shfl_xor(mv, off, 32);
            const int oi = __shfl_xor(mi, off, 32);
            if (ov > mv || (ov == mv && oi < mi)) { mv = ov; mi = oi; }
        }
        mv = __shfl(mv, 0, 64);   // lanes 32-63 held -inf junk: broadcast lane 0
        mi = __shfl(mi, 0, 64);
        tv[p] = mv; ti[p] = mi;
        if (li == mi) { lv = -3e30f; li = 0x7fffffff; }   // demote owner
    }

    const float xn = xnorm[r];
    const f32x4 xv4 = *(const f32x4*)&x[(size_t)r * DIM + lane * 4];

    int ind;
    if (tv[1] < tv[0] - DELTA) {
        ind = ti[0];                       // gap certified: approx argmax is exact
    } else {
        float bv = -3e30f; int bi = 0x7fffffff;
#pragma unroll
        for (int p = 0; p < 4; ++p) {
            if (tv[p] >= tv[0] - DELTA) {  // wave-uniform
                const int idx = ti[p];
                const f32x4 ev = *(const f32x4*)&embed[(size_t)idx * DIM + lane * 4];
                const float d = xv4[0]*ev[0] + xv4[1]*ev[1] + xv4[2]*ev[2] + xv4[3]*ev[3];
                const float s = waveReduceSum(d);
                const float exact = s / (xn * enorm[idx]);
                if (exact > bv || (exact == bv && idx < bi)) { bv = exact; bi = idx; }
            }
        }
        ind = bi;
    }

    if (lane == 0) {
        ind_out[r] = (float)ind;
        atomicAdd(&bins[ind], 1.0f);
    }
    const f32x4 e = *(const f32x4*)&embed[(size_t)ind * DIM + lane * 4];
    *(f32x4*)&quantize[(size_t)r * DIM + lane * 4] = e;
    atomicAdd(&embed_sum[(size_t)ind * DIM + lane * 4 + 0], xv4[0] / xn);
    atomicAdd(&embed_sum[(size_t)ind * DIM + lane * 4 + 1], xv4[1] / xn);
    atomicAdd(&embed_sum[(size_t)ind * DIM + lane * 4 + 2], xv4[2] / xn);
    atomicAdd(&embed_sum[(size_t)ind * DIM + lane * 4 + 3], xv4[3] / xn);
}

// ---------- EMA update (en recomputed inline) ----------
__global__ __launch_bounds__(256) void k_update(const float* __restrict__ embed,
    const float* __restrict__ embed_sum, const float* __restrict__ bins,
    float* __restrict__ embed_new, int K)
{
    const int w = threadIdx.x >> 6, lane = threadIdx.x & 63;
    const int k = blockIdx.x * 4 + w;
    if (k >= K) return;
    f32x4 e = *(const f32x4*)&embed[(size_t)k * DIM + lane * 4];
    float sse = waveReduceSum(e[0]*e[0] + e[1]*e[1] + e[2]*e[2] + e[3]*e[3]);
    const float ne = fmaxf(sqrtf(sse), 1e-12f);

    const float b = bins[k];
    const float bs = (b == 0.f) ? 1.f : b;
    f32x4 s = *(const f32x4*)&embed_sum[(size_t)k * DIM + lane * 4];
    f32x4 vv;
    vv[0] = s[0] / bs; vv[1] = s[1] / bs; vv[2] = s[2] / bs; vv[3] = s[3] / bs;
    float ssv = waveReduceSum(vv[0]*vv[0] + vv[1]*vv[1] + vv[2]*vv[2] + vv[3]*vv[3]);
    const float nv = fmaxf(sqrtf(ssv), 1e-12f);

    f32x4 o;
#pragma unroll
    for (int c = 0; c < 4; ++c) {
        const float norm_c = (b == 0.f) ? (e[c] / ne) : (vv[c] / nv);
        o[c] = 0.8f * e[c] + 0.2f * norm_c;
    }
    *(f32x4*)&embed_new[(size_t)k * DIM + lane * 4] = o;
}

extern "C" void kernel_launch(void* const* d_in, const int* in_sizes, int n_in,
                              void* d_out, int out_size, void* d_ws, size_t ws_size,
                              hipStream_t stream) {
    const float* x = (const float*)d_in[0];
    const float* embed = (const float*)d_in[1];
    const int N = in_sizes[0] / DIM;   // 16384
    const int K = in_sizes[1] / DIM;   // 8192

    float* quantize  = (float*)d_out;
    float* ind_out   = quantize + (size_t)N * DIM;
    float* embed_new = ind_out + N;

    char* ws = (char*)d_ws;
    _Float16* fnh = (_Float16*)ws;                               // 8 MB
    _Float16* enh = (_Float16*)(ws + (size_t)N * DIM * 2);       // 4 MB
    char* p = ws + (size_t)N * DIM * 2 + (size_t)K * DIM * 2;
    float* xnorm    = (float*)p;                 p += (size_t)N * 4;
    float* enorm    = (float*)p;                 p += (size_t)K * 4;
    float* cand_val = (float*)p;                 p += (size_t)N * SPLITS * 4 * 4;
    int*   cand_idx = (int*)p;
    // embed_sum/bins alias fnh/enh (dead after k_gemm; merge uses raw x/embed)
    float* embed_sum = (float*)ws;                       // 8 MB = fnh region
    float* bins      = (float*)(ws + (size_t)N * DIM * 2);  // enh region

    k_prep<<<(N + 3) / 4, 256, 0, stream>>>(x, fnh, xnorm, N);
    k_prep<<<(K + 3) / 4, 256, 0, stream>>>(embed, enh, enorm, K);

    dim3 grid(N / NROWS_TILE, SPLITS);
    k_gemm<<<grid, 256, 0, stream>>>(fnh, enh, cand_val, cand_idx);

    hipMemsetAsync(embed_sum, 0, (size_t)K * DIM * sizeof(float), stream);
    hipMemsetAsync(bins, 0, (size_t)K * sizeof(float), stream);

    k_merge<<<(N + 3) / 4, 256, 0, stream>>>(x, embed, cand_val, cand_idx, xnorm,
                                             enorm, quantize, ind_out, embed_sum, bins);
    k_update<<<(K + 3) / 4, 256, 0, stream>>>(embed, embed_sum, bins, embed_new, K);
}

// Round 16
// 179.210 us; speedup vs baseline: 3.0558x; 1.0342x over previous
//
#include <hip/hip_runtime.h>
#include <math.h>

#define DIM 256
#define NROWS_TILE 256              // 4 waves x 64 rows
#define SPLITS 8
#define CODES_PER_SPLIT 1024        // K / SPLITS
#define CCH 32                      // codes per phase (full K=256 staged)
#define NPH (CODES_PER_SPLIT / CCH) // 32 phases
#define BUF_F16 8192                // 16 KB: 16 frags x 512 f16 (Bh only)
#define DELTA 2.2e-3f               // > 2x rigorous |exact - hi.hi| bound (9.8e-4)

typedef __attribute__((ext_vector_type(8))) _Float16 f16x8;
typedef __attribute__((ext_vector_type(4))) _Float16 f16x4;
typedef __attribute__((ext_vector_type(4))) float f32x4;

__device__ __forceinline__ void gload16(const void* g, void* l) {
    __builtin_amdgcn_global_load_lds(
        (const __attribute__((address_space(1))) void*)g,
        (__attribute__((address_space(3))) void*)l, 16, 0, 0);
}

__device__ __forceinline__ float waveReduceSum(float v) {
#pragma unroll
    for (int off = 32; off >= 1; off >>= 1) v += __shfl_xor(v, off, 64);
    return v;
}

// ---------- prep (fused): l2norm+f16 encode for BOTH x and embed, plus
// zero embed_sum|bins (contiguous region) -- replaces 2 preps + 2 memsets ----
__global__ __launch_bounds__(256) void k_prep_all(
    const float* __restrict__ x, const float* __restrict__ embed,
    _Float16* __restrict__ fnh, _Float16* __restrict__ enh,
    float* __restrict__ xnorm, float* __restrict__ enorm,
    float* __restrict__ zero_region, int nzero4, int N, int K)
{
    const int w = threadIdx.x >> 6, lane = threadIdx.x & 63;
    const int r = blockIdx.x * 4 + w;

    // zeroing: one conditional float4 store per thread
    const int gid = blockIdx.x * 256 + threadIdx.x;
    if (gid < nzero4)
        *(f32x4*)&zero_region[(size_t)gid * 4] = (f32x4){0.f, 0.f, 0.f, 0.f};

    if (r >= N + K) return;
    const bool isX = (r < N);
    const float* src = isX ? &x[(size_t)r * DIM] : &embed[(size_t)(r - N) * DIM];
    f32x4 v = *(const f32x4*)&src[lane * 4];
    float ss = waveReduceSum(v[0]*v[0] + v[1]*v[1] + v[2]*v[2] + v[3]*v[3]);
    const float n = fmaxf(sqrtf(ss), 1e-12f);
    if (lane == 0) { if (isX) xnorm[r] = n; else enorm[r - N] = n; }
    f16x4 h;
#pragma unroll
    for (int c = 0; c < 4; ++c) h[c] = (_Float16)(v[c] / n);
    _Float16* dst = isX ? &fnh[(size_t)r * DIM] : &enh[(size_t)(r - N) * DIM];
    *(f16x4*)&dst[lane * 4] = h;
}

// ---------- main: hi-only f16 MFMA GEMM-BT, 64 rows/wave ----------
// grid: (N/256, SPLITS) = 512 blocks = exactly 2/CU. 4 waves; wave owns 64
// rows x K=256 in regs (Ah[4][8], 128 VGPR). Phase = 32 codes x 256 k (Bh
// only) = 16 KB, ring-2, publish protocol: vmcnt(0)->barrier->stage->compute.
// vs R15: B-LDS port bytes per staged byte HALVED (each frag serves 64 rows),
// port ~41us -> ~20us. Top-2/slot + top-4/(row,split) certified-refine as R15.
__global__ __launch_bounds__(256, 2) void k_gemm(
    const _Float16* __restrict__ fnh, const _Float16* __restrict__ enh,
    float* __restrict__ cand_val, int* __restrict__ cand_idx)
{
    // buf: frag s (ch=s>>3, kc=s&7) at s*512; slot lane*8 =
    // enh[(cb+ch*16+(lane&15))*256 + kc*32 + (lane>>4)*8]
    __shared__ _Float16 smem[2][BUF_F16];   // 2 x 16 KB

    const int t = threadIdx.x;
    const int w = t >> 6, lane = t & 63;
    const int rbase = blockIdx.x * NROWS_TILE;
    const int cbase = blockIdx.y * CODES_PER_SPLIT;
    const int koff = (lane >> 4) * 8;

    // ---- A panel (hi only): wave w rows rbase+w*64 .. +63, full K ----
    f16x8 Ah[4][8];
    {
        const size_t arow = (size_t)(rbase + w * 64 + (lane & 15)) * DIM;
#pragma unroll
        for (int i = 0; i < 4; ++i)
#pragma unroll
            for (int kc = 0; kc < 8; ++kc)
                Ah[i][kc] = *(const f16x8*)&fnh[arow + (size_t)i * 16 * DIM + kc * 32 + koff];
    }
    asm volatile("s_waitcnt vmcnt(0)" ::: "memory");   // A done; vmcnt clean

    // staging roles: wave w stages frags w*4..w*4+3 (ch = w>>1, kc base = (w&1)*4)
    const int chbase = (w >> 1) * 16;
    const int kcb = (w & 1) * 4;
    const int dstoff = w * 2048;
    const _Float16* gptr = enh + (size_t)(cbase + chbase + (lane & 15)) * DIM + kcb * 32 + koff;

    // per-lane-slot top-2 tracking (slot = (i,rg); code = stored + (lane&15))
    float v1[4][4], v2[4][4];
    int   c1[4][4], c2[4][4];
#pragma unroll
    for (int i = 0; i < 4; ++i)
#pragma unroll
        for (int rg = 0; rg < 4; ++rg) {
            v1[i][rg] = -2.0f; v2[i][rg] = -2.5f;
            c1[i][rg] = 0;     c2[i][rg] = 0;
        }

    const f32x4 ZERO4 = (f32x4){0.f, 0.f, 0.f, 0.f};

    // prologue: chunk 0 in flight
    {
        _Float16* l0 = &smem[0][dstoff];
#pragma unroll
        for (int q = 0; q < 4; ++q)
            gload16(gptr + q * 32, l0 + q * 512);
        gptr += CCH * DIM;
    }

#pragma unroll 1
    for (int c = 0; c < NPH; ++c) {
        const int buf = c & 1;
        asm volatile("s_waitcnt vmcnt(0)" ::: "memory");   // publish own loads
        __builtin_amdgcn_s_barrier();
        if (c + 1 < NPH) {
            _Float16* l0 = &smem[buf ^ 1][dstoff];
#pragma unroll
            for (int q = 0; q < 4; ++q)
                gload16(gptr + q * 32, l0 + q * 512);
            gptr += CCH * DIM;
        }

        const _Float16* bufp = &smem[buf][0];
        f32x4 acc[2][4];   // [ch][i]

#pragma unroll
        for (int s = 0; s < 16; ++s) {
            const int ch = s >> 3;
            const int kc = s & 7;
            const f16x8 Bh = *(const f16x8*)(bufp + s * 512 + lane * 8);
            if (kc == 0) {
#pragma unroll
                for (int i = 0; i < 4; ++i)
                    acc[ch][i] = __builtin_amdgcn_mfma_f32_16x16x32_f16(Ah[i][0], Bh, ZERO4, 0, 0, 0);
            } else {
#pragma unroll
                for (int i = 0; i < 4; ++i)
                    acc[ch][i] = __builtin_amdgcn_mfma_f32_16x16x32_f16(Ah[i][kc], Bh, acc[ch][i], 0, 0, 0);
            }
        }

        // top-2 update per slot; codes ascend per lane -> strict > keeps first
        const int cb = cbase + c * CCH;
#pragma unroll
        for (int ch = 0; ch < 2; ++ch)
#pragma unroll
            for (int i = 0; i < 4; ++i)
#pragma unroll
                for (int rg = 0; rg < 4; ++rg) {
                    const float vv = acc[ch][i][rg];
                    const int cd = cb + ch * 16;
                    const bool gt1 = vv > v1[i][rg];
                    const bool gt2 = vv > v2[i][rg];
                    const float nv2 = gt1 ? v1[i][rg] : (gt2 ? vv : v2[i][rg]);
                    const int   nc2 = gt1 ? c1[i][rg] : (gt2 ? cd : c2[i][rg]);
                    v2[i][rg] = nv2; c2[i][rg] = nc2;
                    v1[i][rg] = gt1 ? vv : v1[i][rg];
                    c1[i][rg] = gt1 ? cd : c1[i][rg];
                }
    }

    // epilogue: per slot, extract top-4 of the 16-lane code group
#pragma unroll
    for (int i = 0; i < 4; ++i)
#pragma unroll
        for (int rg = 0; rg < 4; ++rg) {
            float lv1 = v1[i][rg], lv2 = v2[i][rg];
            int   li1 = c1[i][rg] + (lane & 15);
            int   li2 = c2[i][rg] + (lane & 15);
            const int r = rbase + w * 64 + i * 16 + (lane >> 4) * 4 + rg;
            const size_t base = ((size_t)r * SPLITS + blockIdx.y) * 4;
#pragma unroll
            for (int p = 0; p < 4; ++p) {
                float mv = lv1; int mi = li1;
#pragma unroll
                for (int off = 1; off < 16; off <<= 1) {
                    const float ov = __shfl_xor(mv, off, 16);
                    const int oi = __shfl_xor(mi, off, 16);
                    if (ov > mv || (ov == mv && oi < mi)) { mv = ov; mi = oi; }
                }
                if ((lane & 15) == 0) {
                    cand_val[base + p] = mv;
                    cand_idx[base + p] = mi;
                }
                if (li1 == mi) {   // demote owner (indices unique)
                    lv1 = lv2; li1 = li2;
                    lv2 = -3e30f; li2 = 0x7fffffff;
                }
            }
        }
}

// ---------- merge: top-4 global, certified refine, gather + scatter ----------
__global__ __launch_bounds__(256) void k_merge(
    const float* __restrict__ x, const float* __restrict__ embed,
    const float* __restrict__ cand_val, const int* __restrict__ cand_idx,
    const float* __restrict__ xnorm, const float* __restrict__ enorm,
    float* __restrict__ quantize, float* __restrict__ ind_out,
    float* __restrict__ embed_sum, float* __restrict__ bins)
{
    const int w = threadIdx.x >> 6, lane = threadIdx.x & 63;
    const int r = blockIdx.x * 4 + w;
    const int NC = SPLITS * 4;   // 32 candidates

    float lv = -3e30f; int li = 0x7fffffff;
    if (lane < NC) {
        lv = cand_val[(size_t)r * NC + lane];
        li = cand_idx[(size_t)r * NC + lane];
    }
    float tv[4]; int ti[4];
#pragma unroll
    for (int p = 0; p < 4; ++p) {
        float mv = lv; int mi = li;
#pragma unroll
        for (int off = 1; off < 32; off <<= 1) {
            const float ov = __shfl_xor(mv, off, 32);
            const int oi = __shfl_xor(mi, off, 32);
            if (ov > mv || (ov == mv && oi < mi)) { mv = ov; mi = oi; }
        }
        mv = __shfl(mv, 0, 64);   // lanes 32-63 held -inf junk: broadcast lane 0
        mi = __shfl(mi, 0, 64);
        tv[p] = mv; ti[p] = mi;
        if (li == mi) { lv = -3e30f; li = 0x7fffffff; }   // demote owner
    }

    const float xn = xnorm[r];
    const f32x4 xv4 = *(const f32x4*)&x[(size_t)r * DIM + lane * 4];

    int ind;
    if (tv[1] < tv[0] - DELTA) {
        ind = ti[0];                       // gap certified: approx argmax is exact
    } else {
        float bv = -3e30f; int bi = 0x7fffffff;
#pragma unroll
        for (int p = 0; p < 4; ++p) {
            if (tv[p] >= tv[0] - DELTA) {  // wave-uniform
                const int idx = ti[p];
                const f32x4 ev = *(const f32x4*)&embed[(size_t)idx * DIM + lane * 4];
                const float d = xv4[0]*ev[0] + xv4[1]*ev[1] + xv4[2]*ev[2] + xv4[3]*ev[3];
                const float s = waveReduceSum(d);
                const float exact = s / (xn * enorm[idx]);
                if (exact > bv || (exact == bv && idx < bi)) { bv = exact; bi = idx; }
            }
        }
        ind = bi;
    }

    if (lane == 0) {
        ind_out[r] = (float)ind;
        atomicAdd(&bins[ind], 1.0f);
    }
    const f32x4 e = *(const f32x4*)&embed[(size_t)ind * DIM + lane * 4];
    *(f32x4*)&quantize[(size_t)r * DIM + lane * 4] = e;
    atomicAdd(&embed_sum[(size_t)ind * DIM + lane * 4 + 0], xv4[0] / xn);
    atomicAdd(&embed_sum[(size_t)ind * DIM + lane * 4 + 1], xv4[1] / xn);
    atomicAdd(&embed_sum[(size_t)ind * DIM + lane * 4 + 2], xv4[2] / xn);
    atomicAdd(&embed_sum[(size_t)ind * DIM + lane * 4 + 3], xv4[3] / xn);
}

// ---------- EMA update (en recomputed inline) ----------
__global__ __launch_bounds__(256) void k_update(const float* __restrict__ embed,
    const float* __restrict__ embed_sum, const float* __restrict__ bins,
    float* __restrict__ embed_new, int K)
{
    const int w = threadIdx.x >> 6, lane = threadIdx.x & 63;
    const int k = blockIdx.x * 4 + w;
    if (k >= K) return;
    f32x4 e = *(const f32x4*)&embed[(size_t)k * DIM + lane * 4];
    float sse = waveReduceSum(e[0]*e[0] + e[1]*e[1] + e[2]*e[2] + e[3]*e[3]);
    const float ne = fmaxf(sqrtf(sse), 1e-12f);

    const float b = bins[k];
    const float bs = (b == 0.f) ? 1.f : b;
    f32x4 s = *(const f32x4*)&embed_sum[(size_t)k * DIM + lane * 4];
    f32x4 vv;
    vv[0] = s[0] / bs; vv[1] = s[1] / bs; vv[2] = s[2] / bs; vv[3] = s[3] / bs;
    float ssv = waveReduceSum(vv[0]*vv[0] + vv[1]*vv[1] + vv[2]*vv[2] + vv[3]*vv[3]);
    const float nv = fmaxf(sqrtf(ssv), 1e-12f);

    f32x4 o;
#pragma unroll
    for (int c = 0; c < 4; ++c) {
        const float norm_c = (b == 0.f) ? (e[c] / ne) : (vv[c] / nv);
        o[c] = 0.8f * e[c] + 0.2f * norm_c;
    }
    *(f32x4*)&embed_new[(size_t)k * DIM + lane * 4] = o;
}

extern "C" void kernel_launch(void* const* d_in, const int* in_sizes, int n_in,
                              void* d_out, int out_size, void* d_ws, size_t ws_size,
                              hipStream_t stream) {
    const float* x = (const float*)d_in[0];
    const float* embed = (const float*)d_in[1];
    const int N = in_sizes[0] / DIM;   // 16384
    const int K = in_sizes[1] / DIM;   // 8192

    float* quantize  = (float*)d_out;
    float* ind_out   = quantize + (size_t)N * DIM;
    float* embed_new = ind_out + N;

    char* ws = (char*)d_ws;
    _Float16* fnh = (_Float16*)ws;                               // 8 MB
    _Float16* enh = (_Float16*)(ws + (size_t)N * DIM * 2);       // 4 MB
    char* p = ws + (size_t)N * DIM * 2 + (size_t)K * DIM * 2;
    float* xnorm    = (float*)p;                 p += (size_t)N * 4;
    float* enorm    = (float*)p;                 p += (size_t)K * 4;
    float* cand_val = (float*)p;                 p += (size_t)N * SPLITS * 4 * 4;
    int*   cand_idx = (int*)p;                   p += (size_t)N * SPLITS * 4 * 4;
    float* embed_sum = (float*)p;                // K*DIM floats (8 MB)
    float* bins      = embed_sum + (size_t)K * DIM;   // K floats, contiguous
    const int nzero4 = (K * DIM + K) / 4;        // zero embed_sum|bins as float4s

    k_prep_all<<<(N + K + 3) / 4, 256, 0, stream>>>(x, embed, fnh, enh, xnorm,
                                                    enorm, embed_sum, nzero4, N, K);

    dim3 grid(N / NROWS_TILE, SPLITS);
    k_gemm<<<grid, 256, 0, stream>>>(fnh, enh, cand_val, cand_idx);

    k_merge<<<(N + 3) / 4, 256, 0, stream>>>(x, embed, cand_val, cand_idx, xnorm,
                                             enorm, quantize, ind_out, embed_sum, bins);
    k_update<<<(K + 3) / 4, 256, 0, stream>>>(embed, embed_sum, bins, embed_new, K);
}